// Round 1
// baseline (610.273 us; speedup 1.0000x reference)
//
#include <hip/hip_runtime.h>
#include <stdint.h>

typedef __attribute__((ext_vector_type(8))) short s8v;   // 8 x bf16 MFMA operand
typedef __attribute__((ext_vector_type(4))) float f4v;   // 4 x f32 MFMA acc

__device__ __forceinline__ unsigned short f2bf(float x){
  union { float f; uint32_t u; } v; v.f = x;
  uint32_t r = v.u + 0x7FFFu + ((v.u >> 16) & 1u);   // RNE
  return (unsigned short)(r >> 16);
}
__device__ __forceinline__ float bf2f(unsigned short u){
  union { uint32_t u; float f; } v; v.u = ((uint32_t)u) << 16;
  return v.f;
}

// ---------------- converters ----------------
__global__ __launch_bounds__(256) void k_cvt_feat(const float* __restrict__ in,
                                                  unsigned short* __restrict__ out, int n4){
  int i = blockIdx.x*256 + threadIdx.x;
  if (i >= n4) return;
  f4v v = ((const f4v*)in)[i];
  uint2 p;
  p.x = f2bf(v.x) | ((uint32_t)f2bf(v.y) << 16);
  p.y = f2bf(v.z) | ((uint32_t)f2bf(v.w) << 16);
  ((uint2*)out)[i] = p;
}

// W[k][n] -> Wt[n][k ^ ((n&7)<<3)] bf16 (pre-swizzled, transposed)
__global__ __launch_bounds__(256) void k_cvt_w(const float* __restrict__ W0, const float* __restrict__ W1,
                                               const float* __restrict__ W2,
                                               unsigned short* Wt0, unsigned short* Wt1, unsigned short* Wt2){
  int id = blockIdx.x*256 + threadIdx.x;
  if (id < 128*256){ int n = id >> 8, k = id & 255;
    Wt0[n*256 + (k ^ ((n&7)<<3))] = f2bf(W0[(size_t)k*128 + n]); return; }
  id -= 128*256;
  if (id < 128*128){ int n = id >> 7, k = id & 127;
    Wt1[n*128 + (k ^ ((n&7)<<3))] = f2bf(W1[(size_t)k*128 + n]); return; }
  id -= 128*128;
  if (id < 48*128){ int n = id >> 7, k = id & 127;
    Wt2[n*128 + (k ^ ((n&7)<<3))] = (n < 40) ? f2bf(W2[(size_t)k*40 + n]) : (unsigned short)0; return; }
}

// ---------------- CSR build ----------------
__global__ __launch_bounds__(256) void k_count(
    const int* __restrict__ s0, const int* __restrict__ d0, int e0,
    const int* __restrict__ s1, const int* __restrict__ d1, int e1,
    const int* __restrict__ s2, const int* __restrict__ d2, int e2,
    int* ci0, int* co0, int* ci1, int* co1, int* ci2, int* co2,
    int* p0, int* p1, int* p2){
  int id = blockIdx.x*256 + threadIdx.x;
  if (id < e0){ p0[id] = atomicAdd(&ci0[d0[id]], 1); atomicAdd(&co0[s0[id]], 1); return; }
  id -= e0;
  if (id < e1){ p1[id] = atomicAdd(&ci1[d1[id]], 1); atomicAdd(&co1[s1[id]], 1); return; }
  id -= e1;
  if (id < e2){ p2[id] = atomicAdd(&ci2[d2[id]], 1); atomicAdd(&co2[s2[id]], 1); return; }
}

__global__ __launch_bounds__(1024) void k_scan3(const int* c0, int n0, int* o0,
                                                const int* c1, int n1, int* o1,
                                                const int* c2, int n2, int* o2){
  const int* c; int n; int* o;
  if (blockIdx.x == 0){ c = c0; n = n0; o = o0; }
  else if (blockIdx.x == 1){ c = c1; n = n1; o = o1; }
  else { c = c2; n = n2; o = o2; }
  __shared__ int part[1024];
  int t = threadIdx.x;
  int chunk = (n + 1023) / 1024;
  int beg = t*chunk, end = min(beg + chunk, n);
  int s = 0;
  for (int i = beg; i < end; i++) s += c[i];
  part[t] = s; __syncthreads();
  for (int d = 1; d < 1024; d <<= 1){
    int add = (t >= d) ? part[t-d] : 0;
    __syncthreads();
    part[t] += add;
    __syncthreads();
  }
  int prefix = (t > 0) ? part[t-1] : 0;
  for (int i = beg; i < end; i++){ o[i] = prefix; prefix += c[i]; }
  if (t == 1023) o[n] = part[1023];
}

__global__ __launch_bounds__(256) void k_place(
    const int* __restrict__ s0, const int* __restrict__ d0, int e0,
    const int* __restrict__ s1, const int* __restrict__ d1, int e1,
    const int* __restrict__ s2, const int* __restrict__ d2, int e2,
    const int* o0, const int* o1, const int* o2,
    const int* p0, const int* p1, const int* p2,
    int* r0, int* r1, int* r2){
  int id = blockIdx.x*256 + threadIdx.x;
  if (id < e0){ r0[o0[d0[id]] + p0[id]] = s0[id]; return; }
  id -= e0;
  if (id < e1){ r1[o1[d1[id]] + p1[id]] = s1[id]; return; }
  id -= e1;
  if (id < e2){ r2[o2[d2[id]] + p2[id]] = s2[id]; return; }
}

__global__ __launch_bounds__(256) void k_rsq(const int* ci0, const int* co0, int n0,
                                             const int* ci1, const int* co1, int n1,
                                             const int* ci2, const int* co2, int n2,
                                             float* ri0, float* ro0, float* ri1, float* ro1,
                                             float* ri2, float* ro2){
  int id = blockIdx.x*256 + threadIdx.x;
  if (id < n0){ ri0[id] = rsqrtf((float)max(ci0[id],1)); ro0[id] = rsqrtf((float)max(co0[id],1)); return; }
  id -= n0;
  if (id < n1){ ri1[id] = rsqrtf((float)max(ci1[id],1)); ro1[id] = rsqrtf((float)max(co1[id],1)); return; }
  id -= n1;
  if (id < n2){ ri2[id] = rsqrtf((float)max(ci2[id],1)); ro2[id] = rsqrtf((float)max(co2[id],1)); return; }
}

// ---------------- aggregation: wave per node, gather-sum over CSR ----------------
template<int D>   // 256 or 128
__global__ __launch_bounds__(256) void k_agg(const unsigned short* __restrict__ table,
                                             const int* __restrict__ srt, const int* __restrict__ off,
                                             const float* __restrict__ rsq_out, const float* __restrict__ rsq_in,
                                             unsigned short* __restrict__ outb, int n){
  constexpr int VW = D / 64;
  int wid = threadIdx.x >> 6, lane = threadIdx.x & 63;
  int node = blockIdx.x*4 + wid;
  if (node >= n) return;
  int eb = off[node], ee = off[node+1];
  float acc[VW];
  #pragma unroll
  for (int i = 0; i < VW; i++) acc[i] = 0.f;
  int c0 = lane * VW;
  int e = eb;
  int sNext = (e < ee) ? srt[e] : 0;
  while (e < ee){
    int s = sNext;
    e++;
    sNext = (e < ee) ? srt[e] : 0;
    float w = rsq_out[s];
    const unsigned short* row = table + (size_t)s*D + c0;
    if constexpr (VW == 4){
      ushort4 v = *(const ushort4*)row;
      acc[0] += w * bf2f(v.x); acc[1] += w * bf2f(v.y);
      acc[2] += w * bf2f(v.z); acc[3] += w * bf2f(v.w);
    } else {
      ushort2 v = *(const ushort2*)row;
      acc[0] += w * bf2f(v.x); acc[1] += w * bf2f(v.y);
    }
  }
  float ri = rsq_in[node];
  if constexpr (VW == 4){
    uint2 p;
    p.x = f2bf(acc[0]*ri) | ((uint32_t)f2bf(acc[1]*ri) << 16);
    p.y = f2bf(acc[2]*ri) | ((uint32_t)f2bf(acc[3]*ri) << 16);
    *(uint2*)(outb + (size_t)node*D + c0) = p;
  } else {
    uint32_t p = f2bf(acc[0]*ri) | ((uint32_t)f2bf(acc[1]*ri) << 16);
    *(uint32_t*)(outb + (size_t)node*D + c0) = p;
  }
}

// ---------------- small NN GEMM: out = relu(A @ W + b), A bf16 [M,K], Wt pre-swizzled [NT*16][K]
// outT: bf16 [128][ldOut] pre-swizzled transposed (for next TN GEMM); or outF: f32 [M][Nv]
template<int K, int NT, bool RELU>
__global__ __launch_bounds__(256) void k_gemm_nn(const unsigned short* __restrict__ A,
                                                 const unsigned short* __restrict__ Wt,
                                                 const float* __restrict__ bias,
                                                 unsigned short* __restrict__ outT,
                                                 float* __restrict__ outF,
                                                 int M, int ldOut, int Nv){
  __shared__ __align__(16) unsigned short lW[NT*16*K];
  for (int i = threadIdx.x; i < NT*16*K/8; i += 256)
    ((uint4*)lW)[i] = ((const uint4*)Wt)[i];
  __syncthreads();
  int lane = threadIdx.x & 63, w = threadIdx.x >> 6;
  int mb = blockIdx.x*64 + w*16;
  int row = mb + (lane & 15);
  int kg = lane >> 4;
  f4v acc[NT];
  #pragma unroll
  for (int nt = 0; nt < NT; nt++) acc[nt] = (f4v){0.f,0.f,0.f,0.f};
  for (int k0 = 0; k0 < K; k0 += 32){
    s8v a = {0,0,0,0,0,0,0,0};
    if (row < M) a = *(const s8v*)(A + (size_t)row*K + k0 + kg*8);
    #pragma unroll
    for (int nt = 0; nt < NT; nt++){
      int n = nt*16 + (lane & 15);
      s8v b = *(const s8v*)(lW + n*K + ((k0 + kg*8) ^ ((n&7)<<3)));
      acc[nt] = __builtin_amdgcn_mfma_f32_16x16x32_bf16(a, b, acc[nt], 0, 0, 0);
    }
  }
  int m4 = mb + kg*4;
  #pragma unroll
  for (int nt = 0; nt < NT; nt++){
    int n = nt*16 + (lane & 15);
    float bv = (n < Nv) ? bias[n] : 0.f;
    float v0 = acc[nt][0] + bv, v1 = acc[nt][1] + bv, v2 = acc[nt][2] + bv, v3 = acc[nt][3] + bv;
    if (RELU){ v0 = fmaxf(v0,0.f); v1 = fmaxf(v1,0.f); v2 = fmaxf(v2,0.f); v3 = fmaxf(v3,0.f); }
    if (outT){
      if (m4 >= M){ v0 = v1 = v2 = v3 = 0.f; }      // zero pad rows (determinism + safe MFMA pad)
      uint2 p;
      p.x = f2bf(v0) | ((uint32_t)f2bf(v1) << 16);
      p.y = f2bf(v2) | ((uint32_t)f2bf(v3) << 16);
      *(uint2*)(outT + (size_t)n*ldOut + (m4 ^ ((n&7)<<3))) = p;
    } else {
      float vv[4] = {v0, v1, v2, v3};
      #pragma unroll
      for (int r = 0; r < 4; r++){
        int m = m4 + r;
        if (m < M && n < Nv) outF[(size_t)m*Nv + n] = vv[r];
      }
    }
  }
}

// ---------------- TN GEMM: part[s][m][n] = sum_k P[k][m] * h[k][n]
// P f32 [K][ldP=M]; Bsw: bf16 pre-swizzled transposed h [128][ldB]; K-split over gridDim.y
__global__ __launch_bounds__(256) void k_tn(const float* __restrict__ P, int ldP, int M, int K,
                                            const unsigned short* __restrict__ Bsw, int ldB,
                                            float* __restrict__ part, int Mp,
                                            int KPtiles, int chunkTiles){
  __shared__ __align__(16) unsigned short lA[64*64];
  __shared__ __align__(16) unsigned short lB[128*64];
  int mb = blockIdx.x*64;
  int s  = blockIdx.y;
  int tbeg = s * chunkTiles;
  int tend = min(tbeg + chunkTiles, KPtiles);
  int tid = threadIdx.x, lane = tid & 63, w = tid >> 6;
  int wmBase = (w >> 1)*32, wnBase = (w & 1)*64;
  f4v acc[2][4];
  #pragma unroll
  for (int mt = 0; mt < 2; mt++)
    #pragma unroll
    for (int nt = 0; nt < 4; nt++) acc[mt][nt] = (f4v){0.f,0.f,0.f,0.f};

  for (int t = tbeg; t < tend; t++){
    int k0 = t*64;
    { // stage A: P[k0..k0+64)[mb..mb+64) -> lA[m][k^s(m)] bf16 (transpose + convert)
      int m2 = (tid & 31)*2;
      int kk = (tid >> 5)*2;
      int gm = mb + m2;
      #pragma unroll
      for (int p = 0; p < 4; p++){
        int kr = kk + p*16;
        int gk = k0 + kr;
        float2 r0 = {0.f,0.f}, r1 = {0.f,0.f};
        bool mok = (gm < M);            // M is even; gm, gm+1 valid together
        if (mok && gk     < K) r0 = *(const float2*)(P + (size_t)gk*ldP + gm);
        if (mok && gk + 1 < K) r1 = *(const float2*)(P + (size_t)(gk+1)*ldP + gm);
        uint32_t w0 = f2bf(r0.x) | ((uint32_t)f2bf(r1.x) << 16);
        uint32_t w1 = f2bf(r0.y) | ((uint32_t)f2bf(r1.y) << 16);
        *(uint32_t*)(lA + m2*64     + (kr ^ ((m2&7)<<3)))     = w0;
        *(uint32_t*)(lA + (m2+1)*64 + (kr ^ (((m2+1)&7)<<3))) = w1;
      }
    }
    { // stage B: linear 16B copies (global already swizzled)
      int r  = tid >> 3;
      int cb = (tid & 7)*8;
      #pragma unroll
      for (int p = 0; p < 4; p++){
        int n = p*32 + r;
        uint4 v = *(const uint4*)(Bsw + (size_t)n*ldB + k0 + cb);
        *(uint4*)(lB + n*64 + cb) = v;
      }
    }
    __syncthreads();
    #pragma unroll
    for (int ks = 0; ks < 2; ks++){
      int kbase = ks*32 + (lane >> 4)*8;
      s8v a[2];
      #pragma unroll
      for (int mt = 0; mt < 2; mt++){
        int m = wmBase + mt*16 + (lane & 15);
        a[mt] = *(const s8v*)(lA + m*64 + (kbase ^ ((m&7)<<3)));
      }
      #pragma unroll
      for (int nt = 0; nt < 4; nt++){
        int n = wnBase + nt*16 + (lane & 15);
        s8v b = *(const s8v*)(lB + n*64 + (kbase ^ ((n&7)<<3)));
        #pragma unroll
        for (int mt = 0; mt < 2; mt++)
          acc[mt][nt] = __builtin_amdgcn_mfma_f32_16x16x32_bf16(a[mt], b, acc[mt][nt], 0, 0, 0);
      }
    }
    __syncthreads();
  }
  float* dst = part + (size_t)s*Mp*128;
  #pragma unroll
  for (int mt = 0; mt < 2; mt++){
    int m4 = mb + wmBase + mt*16 + (lane >> 4)*4;
    #pragma unroll
    for (int nt = 0; nt < 4; nt++){
      int n = wnBase + nt*16 + (lane & 15);
      #pragma unroll
      for (int r = 0; r < 4; r++)
        dst[(size_t)(m4 + r)*128 + n] = acc[mt][nt][r];
    }
  }
}

// ---------------- reduce k-split partials -> bf16 table (+ optional f32 output) ----------------
__global__ __launch_bounds__(256) void k_reduce(const float* __restrict__ part, int Mp, int S, int M,
                                                unsigned short* __restrict__ gb, float* __restrict__ embOut){
  int i = blockIdx.x*256 + threadIdx.x;    // index of f32x4 group
  int total = Mp*32;
  if (i >= total) return;
  f4v sum = (f4v){0.f,0.f,0.f,0.f};
  for (int p = 0; p < S; p++)
    sum += ((const f4v*)(part + (size_t)p*Mp*128))[i];
  int m = (i*4) >> 7;
  if (m < M){
    uint2 pk;
    pk.x = f2bf(sum.x) | ((uint32_t)f2bf(sum.y) << 16);
    pk.y = f2bf(sum.z) | ((uint32_t)f2bf(sum.w) << 16);
    ((uint2*)gb)[i] = pk;
    if (embOut) ((f4v*)embOut)[i] = sum;
  }
}

// ---------------- launcher ----------------
extern "C" void kernel_launch(void* const* d_in, const int* in_sizes, int n_in,
                              void* d_out, int out_size, void* d_ws, size_t ws_size,
                              hipStream_t stream){
  const float* features = (const float*)d_in[0];
  const int* src0 = (const int*)d_in[1];
  const int* dst0 = (const int*)d_in[2];
  const int* src1 = (const int*)d_in[3];
  const int* dst1 = (const int*)d_in[4];
  const int* src2 = (const int*)d_in[5];
  const int* dst2 = (const int*)d_in[6];
  const float* P1 = (const float*)d_in[7];
  const float* P2 = (const float*)d_in[8];
  const float* W0 = (const float*)d_in[9];
  const float* b0 = (const float*)d_in[10];
  const float* W1 = (const float*)d_in[11];
  const float* b1 = (const float*)d_in[12];
  const float* W2 = (const float*)d_in[13];
  const float* b2 = (const float*)d_in[14];
  float* out = (float*)d_out;

  const int IND = 256, HID = 128, NC = 40;
  const int n0 = in_sizes[0] / IND;                 // 20000
  const int e0 = in_sizes[1], e1 = in_sizes[3], e2 = in_sizes[5];
  const int n1 = (int)((size_t)in_sizes[7] / n0);   // 10000
  const int n2 = (int)((size_t)in_sizes[8] / n1);   // 5000

  const int g0   = (n0 + 63)/64;       // 313
  const int g1   = (n1 + 63)/64;       // 157
  const int g2   = (n2 + 63)/64;       // 79
  const int ld1  = g0*64;              // 20032  (h1t row length = padded n0)
  const int ld2  = g1*64;              // 10048
  const int Mp1  = g1*64;              // 10048  (padded n1)
  const int Mp2  = g2*64;              // 5056
  const int S1 = 6, S2 = 8;
  const int KPt1 = g0;                 // 313 K-tiles for P1 GEMM
  const int KPt2 = g1;                 // 157
  const int cT1 = (KPt1 + S1 - 1)/S1;  // 53
  const int cT2 = (KPt2 + S2 - 1)/S2;  // 20

  // ---- workspace layout ----
  size_t o = 0;
  auto ALLOC = [&](size_t bytes)->size_t{ size_t r = o; o += (bytes + 255) & ~(size_t)255; return r; };
  size_t o_cnt = ALLOC((size_t)(2*n0 + 2*n1 + 2*n2)*4);
  size_t o_off = ALLOC((size_t)(n0 + n1 + n2 + 3)*4);
  size_t o_pos = ALLOC((size_t)(e0 + e1 + e2)*4);
  size_t o_srt = ALLOC((size_t)(e0 + e1 + e2)*4);
  size_t o_rsq = ALLOC((size_t)(2*n0 + 2*n1 + 2*n2)*4);
  size_t o_wt0 = ALLOC(128*256*2);
  size_t o_wt1 = ALLOC(128*128*2);
  size_t o_wt2 = ALLOC(48*128*2);
  size_t o_g1b = ALLOC((size_t)n1*128*2);
  size_t o_ag1 = ALLOC((size_t)n1*128*2);
  size_t o_h2t = ALLOC((size_t)128*ld2*2);
  size_t o_g2b = ALLOC((size_t)n2*128*2);
  size_t o_ag2 = ALLOC((size_t)n2*128*2);
  size_t o_h1t = ALLOC((size_t)128*ld1*2);
  size_t o_p1  = ALLOC((size_t)S1*Mp1*128*4);
  size_t featb_b = (size_t)n0*IND*2;
  size_t ovl_sz = featb_b*2;                         // featb + agg0b
  size_t p2_sz  = (size_t)S2*Mp2*128*4;
  if (p2_sz > ovl_sz) ovl_sz = p2_sz;
  size_t o_ovl = ALLOC(ovl_sz);
  if (ws_size < o) return;                           // ws too small -> fail loudly

  char* B = (char*)d_ws;
  int* ci0 = (int*)(B + o_cnt); int* co0 = ci0 + n0;
  int* ci1 = co0 + n0;          int* co1 = ci1 + n1;
  int* ci2 = co1 + n1;          int* co2 = ci2 + n2;
  int* off0 = (int*)(B + o_off); int* off1 = off0 + n0 + 1; int* off2 = off1 + n1 + 1;
  int* pos0 = (int*)(B + o_pos); int* pos1 = pos0 + e0; int* pos2 = pos1 + e1;
  int* srt0 = (int*)(B + o_srt); int* srt1 = srt0 + e0; int* srt2 = srt1 + e1;
  float* ri0 = (float*)(B + o_rsq); float* ro0 = ri0 + n0;
  float* ri1 = ro0 + n0; float* ro1 = ri1 + n1;
  float* ri2 = ro1 + n1; float* ro2 = ri2 + n2;
  unsigned short* wt0 = (unsigned short*)(B + o_wt0);
  unsigned short* wt1 = (unsigned short*)(B + o_wt1);
  unsigned short* wt2 = (unsigned short*)(B + o_wt2);
  unsigned short* g1b = (unsigned short*)(B + o_g1b);
  unsigned short* ag1 = (unsigned short*)(B + o_ag1);
  unsigned short* h2t = (unsigned short*)(B + o_h2t);
  unsigned short* g2b = (unsigned short*)(B + o_g2b);
  unsigned short* ag2 = (unsigned short*)(B + o_ag2);
  unsigned short* h1t = (unsigned short*)(B + o_h1t);
  float* part1 = (float*)(B + o_p1);
  unsigned short* featb = (unsigned short*)(B + o_ovl);
  unsigned short* ag0   = featb + featb_b/2;
  float* part2 = (float*)(B + o_ovl);                // overlays featb/ag0 (dead by then)

  float* emb = out + (size_t)n2*NC;                  // output 1 region

  // 1. zero counters
  hipMemsetAsync(B + o_cnt, 0, (size_t)(2*n0 + 2*n1 + 2*n2)*4, stream);
  // 2. convert weights + features
  k_cvt_w<<<216, 256, 0, stream>>>(W0, W1, W2, wt0, wt1, wt2);
  int n4f = n0*IND/4;
  k_cvt_feat<<<(n4f + 255)/256, 256, 0, stream>>>(features, featb, n4f);
  // 3. CSR build (all levels batched)
  int eTot = e0 + e1 + e2;
  k_count<<<(eTot + 255)/256, 256, 0, stream>>>(src0, dst0, e0, src1, dst1, e1, src2, dst2, e2,
                                                ci0, co0, ci1, co1, ci2, co2, pos0, pos1, pos2);
  k_scan3<<<3, 1024, 0, stream>>>(ci0, n0, off0, ci1, n1, off1, ci2, n2, off2);
  k_place<<<(eTot + 255)/256, 256, 0, stream>>>(src0, dst0, e0, src1, dst1, e1, src2, dst2, e2,
                                                off0, off1, off2, pos0, pos1, pos2, srt0, srt1, srt2);
  k_rsq<<<((n0 + n1 + n2) + 255)/256, 256, 0, stream>>>(ci0, co0, n0, ci1, co1, n1, ci2, co2, n2,
                                                        ri0, ro0, ri1, ro1, ri2, ro2);
  // 4. level 0: aggregate + GEMM0 (writes h1t transposed+swizzled)
  k_agg<256><<<(n0 + 3)/4, 256, 0, stream>>>(featb, srt0, off0, ro0, ri0, ag0, n0);
  k_gemm_nn<256, 8, true><<<g0, 256, 0, stream>>>(ag0, wt0, b0, h1t, nullptr, n0, ld1, HID);
  // 5. P1^T @ h1 (k-split) + reduce -> g1b bf16
  {
    dim3 grid(g1, S1);
    k_tn<<<grid, 256, 0, stream>>>(P1, n1, n1, n0, h1t, ld1, part1, Mp1, KPt1, cT1);
  }
  k_reduce<<<(Mp1*32 + 255)/256, 256, 0, stream>>>(part1, Mp1, S1, n1, g1b, nullptr);
  // 6. level 1
  k_agg<128><<<(n1 + 3)/4, 256, 0, stream>>>(g1b, srt1, off1, ro1, ri1, ag1, n1);
  k_gemm_nn<128, 8, true><<<g1, 256, 0, stream>>>(ag1, wt1, b1, h2t, nullptr, n1, ld2, HID);
  // 7. P2^T @ h2 + reduce -> emb f32 (output 1) + g2b bf16
  {
    dim3 grid(g2, S2);
    k_tn<<<grid, 256, 0, stream>>>(P2, n2, n2, n1, h2t, ld2, part2, Mp2, KPt2, cT2);
  }
  k_reduce<<<(Mp2*32 + 255)/256, 256, 0, stream>>>(part2, Mp2, S2, n2, g2b, emb);
  // 8. level 2: aggregate + GEMM2 -> out[0:n2*NC] f32 (output 0)
  k_agg<128><<<(n2 + 3)/4, 256, 0, stream>>>(g2b, srt2, off2, ro2, ri2, ag2, n2);
  k_gemm_nn<128, 3, false><<<g2, 256, 0, stream>>>(ag2, wt2, b2, nullptr, out, n2, 0, NC);
}

// Round 2
// 610.007 us; speedup vs baseline: 1.0004x; 1.0004x over previous
//
#include <hip/hip_runtime.h>
#include <stdint.h>

typedef __attribute__((ext_vector_type(8))) short s8v;   // 8 x bf16 MFMA operand
typedef __attribute__((ext_vector_type(4))) float f4v;   // 4 x f32 MFMA acc / float4

__device__ __forceinline__ unsigned short f2bf(float x){
  union { float f; uint32_t u; } v; v.f = x;
  uint32_t r = v.u + 0x7FFFu + ((v.u >> 16) & 1u);   // RNE
  return (unsigned short)(r >> 16);
}
__device__ __forceinline__ float bf2f(unsigned short u){
  union { uint32_t u; float f; } v; v.u = ((uint32_t)u) << 16;
  return v.f;
}

__device__ __forceinline__ void gload_lds16(const void* g, void* l){
  __builtin_amdgcn_global_load_lds((const __attribute__((address_space(1))) void*)g,
                                   (__attribute__((address_space(3))) void*)l, 16, 0, 0);
}

// W[k][n] -> Wt[n][k ^ ((n&7)<<3)] bf16 (pre-swizzled, transposed)
__global__ __launch_bounds__(256) void k_cvt_w(const float* __restrict__ W0, const float* __restrict__ W1,
                                               const float* __restrict__ W2,
                                               unsigned short* Wt0, unsigned short* Wt1, unsigned short* Wt2){
  int id = blockIdx.x*256 + threadIdx.x;
  if (id < 128*256){ int n = id >> 8, k = id & 255;
    Wt0[n*256 + (k ^ ((n&7)<<3))] = f2bf(W0[(size_t)k*128 + n]); return; }
  id -= 128*256;
  if (id < 128*128){ int n = id >> 7, k = id & 127;
    Wt1[n*128 + (k ^ ((n&7)<<3))] = f2bf(W1[(size_t)k*128 + n]); return; }
  id -= 128*128;
  if (id < 48*128){ int n = id >> 7, k = id & 127;
    Wt2[n*128 + (k ^ ((n&7)<<3))] = (n < 40) ? f2bf(W2[(size_t)k*40 + n]) : (unsigned short)0; return; }
}

// ---------------- CSR build ----------------
__global__ __launch_bounds__(256) void k_count(
    const int* __restrict__ s0, const int* __restrict__ d0, int e0,
    const int* __restrict__ s1, const int* __restrict__ d1, int e1,
    const int* __restrict__ s2, const int* __restrict__ d2, int e2,
    int* ci0, int* co0, int* ci1, int* co1, int* ci2, int* co2,
    int* p0, int* p1, int* p2){
  int id = blockIdx.x*256 + threadIdx.x;
  if (id < e0){ p0[id] = atomicAdd(&ci0[d0[id]], 1); atomicAdd(&co0[s0[id]], 1); return; }
  id -= e0;
  if (id < e1){ p1[id] = atomicAdd(&ci1[d1[id]], 1); atomicAdd(&co1[s1[id]], 1); return; }
  id -= e1;
  if (id < e2){ p2[id] = atomicAdd(&ci2[d2[id]], 1); atomicAdd(&co2[s2[id]], 1); return; }
}

__global__ __launch_bounds__(1024) void k_scan3(const int* c0, int n0, int* o0,
                                                const int* c1, int n1, int* o1,
                                                const int* c2, int n2, int* o2){
  const int* c; int n; int* o;
  if (blockIdx.x == 0){ c = c0; n = n0; o = o0; }
  else if (blockIdx.x == 1){ c = c1; n = n1; o = o1; }
  else { c = c2; n = n2; o = o2; }
  __shared__ int part[1024];
  int t = threadIdx.x;
  int chunk = (n + 1023) / 1024;
  int beg = t*chunk, end = min(beg + chunk, n);
  int s = 0;
  for (int i = beg; i < end; i++) s += c[i];
  part[t] = s; __syncthreads();
  for (int d = 1; d < 1024; d <<= 1){
    int add = (t >= d) ? part[t-d] : 0;
    __syncthreads();
    part[t] += add;
    __syncthreads();
  }
  int prefix = (t > 0) ? part[t-1] : 0;
  for (int i = beg; i < end; i++){ o[i] = prefix; prefix += c[i]; }
  if (t == 1023) o[n] = part[1023];
}

__global__ __launch_bounds__(256) void k_place(
    const int* __restrict__ s0, const int* __restrict__ d0, int e0,
    const int* __restrict__ s1, const int* __restrict__ d1, int e1,
    const int* __restrict__ s2, const int* __restrict__ d2, int e2,
    const int* o0, const int* o1, const int* o2,
    const int* p0, const int* p1, const int* p2,
    int* r0, int* r1, int* r2){
  int id = blockIdx.x*256 + threadIdx.x;
  if (id < e0){ r0[o0[d0[id]] + p0[id]] = s0[id]; return; }
  id -= e0;
  if (id < e1){ r1[o1[d1[id]] + p1[id]] = s1[id]; return; }
  id -= e1;
  if (id < e2){ r2[o2[d2[id]] + p2[id]] = s2[id]; return; }
}

__global__ __launch_bounds__(256) void k_rsq(const int* ci0, const int* co0, int n0,
                                             const int* ci1, const int* co1, int n1,
                                             const int* ci2, const int* co2, int n2,
                                             float* ri0, float* ro0, float* ri1, float* ro1,
                                             float* ri2, float* ro2){
  int id = blockIdx.x*256 + threadIdx.x;
  if (id < n0){ ri0[id] = rsqrtf((float)max(ci0[id],1)); ro0[id] = rsqrtf((float)max(co0[id],1)); return; }
  id -= n0;
  if (id < n1){ ri1[id] = rsqrtf((float)max(ci1[id],1)); ro1[id] = rsqrtf((float)max(co1[id],1)); return; }
  id -= n1;
  if (id < n2){ ri2[id] = rsqrtf((float)max(ci2[id],1)); ro2[id] = rsqrtf((float)max(co2[id],1)); return; }
}

// ---------------- row-scaled NN GEMM: Y[m][NT*16] = scale[m] * (A[m][K] @ W) (bf16 out) ----------------
template<int K, int NT, bool AF32>
__global__ __launch_bounds__(256) void k_gemm_rs(const void* __restrict__ Av,
                                                 const unsigned short* __restrict__ Wt,
                                                 const float* __restrict__ scale,
                                                 unsigned short* __restrict__ Y, int M){
  constexpr int LDY = NT*16;
  __shared__ __align__(16) unsigned short lW[NT*16*K];
  for (int i = threadIdx.x; i < NT*16*K/8; i += 256)
    ((uint4*)lW)[i] = ((const uint4*)Wt)[i];
  __syncthreads();
  int lane = threadIdx.x & 63, w = threadIdx.x >> 6;
  int mb = blockIdx.x*64 + w*16;
  int row = mb + (lane & 15);
  int kg = lane >> 4;
  f4v acc[NT];
  #pragma unroll
  for (int nt = 0; nt < NT; nt++) acc[nt] = (f4v){0.f,0.f,0.f,0.f};
  for (int k0 = 0; k0 < K; k0 += 32){
    s8v a = {0,0,0,0,0,0,0,0};
    if (row < M){
      if (AF32){
        const float* ap = (const float*)Av + (size_t)row*K + k0 + kg*8;
        f4v f0 = *(const f4v*)ap;
        f4v f1 = *(const f4v*)(ap + 4);
        a[0]=(short)f2bf(f0.x); a[1]=(short)f2bf(f0.y); a[2]=(short)f2bf(f0.z); a[3]=(short)f2bf(f0.w);
        a[4]=(short)f2bf(f1.x); a[5]=(short)f2bf(f1.y); a[6]=(short)f2bf(f1.z); a[7]=(short)f2bf(f1.w);
      } else {
        a = *(const s8v*)((const unsigned short*)Av + (size_t)row*K + k0 + kg*8);
      }
    }
    #pragma unroll
    for (int nt = 0; nt < NT; nt++){
      int n = nt*16 + (lane & 15);
      s8v b = *(const s8v*)(lW + n*K + ((k0 + kg*8) ^ ((n&7)<<3)));
      acc[nt] = __builtin_amdgcn_mfma_f32_16x16x32_bf16(a, b, acc[nt], 0, 0, 0);
    }
  }
  int m4 = mb + kg*4;
  #pragma unroll
  for (int nt = 0; nt < NT; nt++){
    int n = nt*16 + (lane & 15);
    #pragma unroll
    for (int r = 0; r < 4; r++){
      int m = m4 + r;
      if (m < M) Y[(size_t)m*LDY + n] = f2bf(acc[nt][r] * scale[m]);
    }
  }
}

// ---------------- aggregation -> transposed+swizzled table: hT[d][node^s(d)] = relu(ri*sum + b) ----------------
__global__ __launch_bounds__(512) void k_aggT(const unsigned short* __restrict__ Y,
                                              const int* __restrict__ srt, const int* __restrict__ off,
                                              const float* __restrict__ ri, const float* __restrict__ bias,
                                              unsigned short* __restrict__ hT, int ld, int n){
  __shared__ unsigned short ls[128*40];     // [dim][node-local], padded row 40
  int tid = threadIdx.x, lane = tid & 63, wid = tid >> 6;
  for (int i = tid; i < 128*40/2; i += 512) ((uint32_t*)ls)[i] = 0;
  __syncthreads();
  int base = blockIdx.x*32;
  int c0 = lane*2;
  for (int i = 0; i < 4; i++){
    int node = base + wid*4 + i;
    if (node < n){
      int eb = off[node], ee = off[node+1];
      float a0 = 0.f, a1 = 0.f;
      int e = eb;
      int sn = (e < ee) ? srt[e] : 0;
      while (e < ee){
        int sc = sn; e++;
        sn = (e < ee) ? srt[e] : 0;
        uint32_t v = *(const uint32_t*)(Y + (size_t)sc*128 + c0);
        a0 += bf2f((unsigned short)v);
        a1 += bf2f((unsigned short)(v >> 16));
      }
      float r = ri[node];
      float h0 = fmaxf(a0*r + bias[c0],   0.f);
      float h1 = fmaxf(a1*r + bias[c0+1], 0.f);
      int nl = node - base;
      ls[c0*40 + nl]     = f2bf(h0);
      ls[(c0+1)*40 + nl] = f2bf(h1);
    }
  }
  __syncthreads();
  int d = tid >> 2, c = tid & 3;            // 512 threads = 128 dims x 4 chunks of 8 nodes
  uint4 v = *(const uint4*)(ls + d*40 + c*8);
  int m8 = base + c*8;
  *(uint4*)(hT + (size_t)d*ld + (m8 ^ ((d&7)<<3))) = v;
}

// ---------------- final aggregation (width 48 -> 40 f32 out, no relu) ----------------
__global__ __launch_bounds__(256) void k_agg2(const unsigned short* __restrict__ Z,
                                              const int* __restrict__ srt, const int* __restrict__ off,
                                              const float* __restrict__ ri, const float* __restrict__ bias,
                                              float* __restrict__ out, int n){
  int lane = threadIdx.x & 63, wid = threadIdx.x >> 6;
  int node = blockIdx.x*4 + wid;
  if (node >= n) return;
  int eb = off[node], ee = off[node+1];
  int c0 = lane*2;
  bool act = lane < 24;
  float a0 = 0.f, a1 = 0.f;
  int e = eb;
  int sn = (e < ee) ? srt[e] : 0;
  while (e < ee){
    int sc = sn; e++;
    sn = (e < ee) ? srt[e] : 0;
    if (act){
      uint32_t v = *(const uint32_t*)(Z + (size_t)sc*48 + c0);
      a0 += bf2f((unsigned short)v);
      a1 += bf2f((unsigned short)(v >> 16));
    }
  }
  if (c0 < 40){
    float r = ri[node];
    float2 o2 = { a0*r + bias[c0], a1*r + bias[c0+1] };
    *(float2*)(out + (size_t)node*40 + c0) = o2;
  }
}

// ---------------- TN GEMM: part[s][m][n] = sum_k P[k][m] * h[k][n]; BM=128, BN=128, BK=64 ----------------
__global__ __launch_bounds__(256) void k_tn(const float* __restrict__ P, int ldP, int M, int K,
                                            const unsigned short* __restrict__ hT, int ld,
                                            float* __restrict__ part, int Mp,
                                            int KPtiles, int chunkTiles){
  __shared__ __align__(16) unsigned short lA[128*64];
  __shared__ __align__(16) unsigned short lB[2][128*64];
  int tid = threadIdx.x, lane = tid & 63, w = tid >> 6;
  int mb = blockIdx.x*128;
  int s  = blockIdx.y;
  int tbeg = s*chunkTiles, tend = min(tbeg + chunkTiles, KPtiles);
  int m2 = (tid & 63)*2;
  int kb = (tid >> 6)*2;
  int gm = mb + m2;
  bool mok = gm < M;                    // M even: gm,gm+1 valid together
  float2 ra[8], rb[8];

  auto LOADA = [&](int t){
    int k0 = t*64;
    #pragma unroll
    for (int p = 0; p < 8; p++){
      int gk = k0 + kb + p*8;
      float2 z = {0.f, 0.f};
      ra[p] = z; rb[p] = z;
      if (mok && gk     < K) ra[p] = *(const float2*)(P + (size_t)gk*ldP + gm);
      if (mok && gk + 1 < K) rb[p] = *(const float2*)(P + (size_t)(gk+1)*ldP + gm);
    }
  };
  auto WRITEA = [&](){
    #pragma unroll
    for (int p = 0; p < 8; p++){
      int kr = kb + p*8;
      uint32_t w0 = f2bf(ra[p].x) | ((uint32_t)f2bf(rb[p].x) << 16);
      uint32_t w1 = f2bf(ra[p].y) | ((uint32_t)f2bf(rb[p].y) << 16);
      *(uint32_t*)(lA + m2*64     + (kr ^ ((m2&7)<<3)))     = w0;
      *(uint32_t*)(lA + (m2+1)*64 + (kr ^ (((m2+1)&7)<<3))) = w1;
    }
  };
  auto ISSUEB = [&](int t, int buf){
    size_t k0b = (size_t)t*64*2;
    char* lbase = (char*)&lB[buf][0];
    #pragma unroll
    for (int it = 0; it < 4; it++){
      int chunkByte = (it*4 + w)*1024;
      int myByte = chunkByte + lane*16;
      int nrow = myByte >> 7;
      int koff = myByte & 127;
      const char* src = (const char*)hT + (size_t)nrow*ld*2 + k0b + koff;
      gload_lds16(src, lbase + chunkByte);
    }
  };

  int wmBase = (w & 1)*64, wnBase = (w >> 1)*64;
  f4v acc[4][4];
  #pragma unroll
  for (int mt = 0; mt < 4; mt++)
    #pragma unroll
    for (int nt = 0; nt < 4; nt++) acc[mt][nt] = (f4v){0.f,0.f,0.f,0.f};

  auto COMPUTE = [&](int buf){
    #pragma unroll
    for (int ks = 0; ks < 2; ks++){
      int kbase = ks*32 + (lane >> 4)*8;
      s8v af[4];
      #pragma unroll
      for (int mt = 0; mt < 4; mt++){
        int m = wmBase + mt*16 + (lane & 15);
        af[mt] = *(const s8v*)(lA + m*64 + (kbase ^ ((m&7)<<3)));
      }
      #pragma unroll
      for (int nt = 0; nt < 4; nt++){
        int nn = wnBase + nt*16 + (lane & 15);
        s8v bf = *(const s8v*)(&lB[buf][0] + nn*64 + (kbase ^ ((nn&7)<<3)));
        #pragma unroll
        for (int mt = 0; mt < 4; mt++)
          acc[mt][nt] = __builtin_amdgcn_mfma_f32_16x16x32_bf16(af[mt], bf, acc[mt][nt], 0, 0, 0);
      }
    }
  };

  LOADA(tbeg);
  ISSUEB(tbeg, 0);
  WRITEA();
  __syncthreads();
  for (int t = tbeg; t < tend; t++){
    int cur = (t - tbeg) & 1;
    bool more = (t + 1 < tend);
    if (more){ ISSUEB(t + 1, cur ^ 1); LOADA(t + 1); }
    COMPUTE(cur);
    __syncthreads();
    if (more) WRITEA();
    __syncthreads();
  }
  float* dst = part + (size_t)s*Mp*128;
  #pragma unroll
  for (int mt = 0; mt < 4; mt++){
    int m4 = mb + wmBase + mt*16 + (lane >> 4)*4;
    #pragma unroll
    for (int nt = 0; nt < 4; nt++){
      int nn = wnBase + nt*16 + (lane & 15);
      #pragma unroll
      for (int r = 0; r < 4; r++)
        dst[(size_t)(m4 + r)*128 + nn] = acc[mt][nt][r];
    }
  }
}

// ---------------- reduce k-split partials -> bf16 row-major (+ optional f32 output) ----------------
__global__ __launch_bounds__(256) void k_reduce(const float* __restrict__ part, int Mp, int S, int M,
                                                unsigned short* __restrict__ gb, float* __restrict__ embOut){
  int i = blockIdx.x*256 + threadIdx.x;    // index of f32x4 group
  int total = Mp*32;
  if (i >= total) return;
  f4v sum = (f4v){0.f,0.f,0.f,0.f};
  for (int p = 0; p < S; p++)
    sum += ((const f4v*)(part + (size_t)p*Mp*128))[i];
  int m = i >> 5;
  if (m < M){
    uint2 pk;
    pk.x = f2bf(sum.x) | ((uint32_t)f2bf(sum.y) << 16);
    pk.y = f2bf(sum.z) | ((uint32_t)f2bf(sum.w) << 16);
    ((uint2*)gb)[i] = pk;
    if (embOut) ((f4v*)embOut)[i] = sum;
  }
}

// ---------------- launcher ----------------
extern "C" void kernel_launch(void* const* d_in, const int* in_sizes, int n_in,
                              void* d_out, int out_size, void* d_ws, size_t ws_size,
                              hipStream_t stream){
  const float* features = (const float*)d_in[0];
  const int* src0 = (const int*)d_in[1];
  const int* dst0 = (const int*)d_in[2];
  const int* src1 = (const int*)d_in[3];
  const int* dst1 = (const int*)d_in[4];
  const int* src2 = (const int*)d_in[5];
  const int* dst2 = (const int*)d_in[6];
  const float* P1 = (const float*)d_in[7];
  const float* P2 = (const float*)d_in[8];
  const float* W0 = (const float*)d_in[9];
  const float* b0 = (const float*)d_in[10];
  const float* W1 = (const float*)d_in[11];
  const float* b1 = (const float*)d_in[12];
  const float* W2 = (const float*)d_in[13];
  const float* b2 = (const float*)d_in[14];
  float* out = (float*)d_out;

  const int IND = 256, NC = 40;
  const int n0 = in_sizes[0] / IND;                 // 20000
  const int e0 = in_sizes[1], e1 = in_sizes[3], e2 = in_sizes[5];
  const int n1 = (int)((size_t)in_sizes[7] / n0);   // 10000
  const int n2 = (int)((size_t)in_sizes[8] / n1);   // 5000

  const int KPt1 = (n0 + 63)/64;       // 313
  const int KPt2 = (n1 + 63)/64;       // 157
  const int ld1  = KPt1*64;            // 20032
  const int ld2  = KPt2*64;            // 10048
  const int Mp1  = ((n1 + 127)/128)*128;  // 10112
  const int Mp2  = ((n2 + 127)/128)*128;  // 5120
  const int S1 = 8, S2 = 12;
  const int cT1 = (KPt1 + S1 - 1)/S1;  // 40
  const int cT2 = (KPt2 + S2 - 1)/S2;  // 14

  // ---- workspace layout ----
  size_t o = 0;
  auto ALLOC = [&](size_t bytes)->size_t{ size_t r = o; o += (bytes + 255) & ~(size_t)255; return r; };
  size_t o_cnt = ALLOC((size_t)(2*n0 + 2*n1 + 2*n2)*4);
  size_t o_off = ALLOC((size_t)(n0 + n1 + n2 + 3)*4);
  size_t o_pos = ALLOC((size_t)(e0 + e1 + e2)*4);
  size_t o_srt = ALLOC((size_t)(e0 + e1 + e2)*4);
  size_t o_rsq = ALLOC((size_t)(2*n0 + 2*n1 + 2*n2)*4);
  size_t o_wt0 = ALLOC(128*256*2);
  size_t o_wt1 = ALLOC(128*128*2);
  size_t o_wt2 = ALLOC(48*128*2);
  size_t o_y0  = ALLOC((size_t)n0*128*2);
  size_t o_h1t = ALLOC((size_t)128*ld1*2);
  size_t o_p1  = ALLOC((size_t)S1*Mp1*128*4);
  size_t o_g1  = ALLOC((size_t)n1*128*2);
  size_t o_y1  = ALLOC((size_t)n1*128*2);
  size_t o_h2t = ALLOC((size_t)128*ld2*2);
  size_t o_p2  = ALLOC((size_t)S2*Mp2*128*4);
  size_t o_emb = ALLOC((size_t)n2*128*2);
  size_t o_z2  = ALLOC((size_t)n2*48*2);
  if (ws_size < o) return;

  char* B = (char*)d_ws;
  int* ci0 = (int*)(B + o_cnt); int* co0 = ci0 + n0;
  int* ci1 = co0 + n0;          int* co1 = ci1 + n1;
  int* ci2 = co1 + n1;          int* co2 = ci2 + n2;
  int* off0 = (int*)(B + o_off); int* off1 = off0 + n0 + 1; int* off2 = off1 + n1 + 1;
  int* pos0 = (int*)(B + o_pos); int* pos1 = pos0 + e0; int* pos2 = pos1 + e1;
  int* srt0 = (int*)(B + o_srt); int* srt1 = srt0 + e0; int* srt2 = srt1 + e1;
  float* ri0 = (float*)(B + o_rsq); float* ro0 = ri0 + n0;
  float* ri1 = ro0 + n0; float* ro1 = ri1 + n1;
  float* ri2 = ro1 + n1; float* ro2 = ri2 + n2;
  unsigned short* wt0 = (unsigned short*)(B + o_wt0);
  unsigned short* wt1 = (unsigned short*)(B + o_wt1);
  unsigned short* wt2 = (unsigned short*)(B + o_wt2);
  unsigned short* Y0  = (unsigned short*)(B + o_y0);
  unsigned short* h1t = (unsigned short*)(B + o_h1t);
  float* part1 = (float*)(B + o_p1);
  unsigned short* g1  = (unsigned short*)(B + o_g1);
  unsigned short* Y1  = (unsigned short*)(B + o_y1);
  unsigned short* h2t = (unsigned short*)(B + o_h2t);
  float* part2 = (float*)(B + o_p2);
  unsigned short* embb = (unsigned short*)(B + o_emb);
  unsigned short* Z2  = (unsigned short*)(B + o_z2);

  float* emb = out + (size_t)n2*NC;                  // output 1 region

  // 1. zero counters + h-table pads
  hipMemsetAsync(B + o_cnt, 0, (size_t)(2*n0 + 2*n1 + 2*n2)*4, stream);
  hipMemsetAsync(h1t, 0, (size_t)128*ld1*2, stream);
  hipMemsetAsync(h2t, 0, (size_t)128*ld2*2, stream);
  // 2. weights
  k_cvt_w<<<216, 256, 0, stream>>>(W0, W1, W2, wt0, wt1, wt2);
  // 3. CSR build (all levels batched)
  int eTot = e0 + e1 + e2;
  k_count<<<(eTot + 255)/256, 256, 0, stream>>>(src0, dst0, e0, src1, dst1, e1, src2, dst2, e2,
                                                ci0, co0, ci1, co1, ci2, co2, pos0, pos1, pos2);
  k_scan3<<<3, 1024, 0, stream>>>(ci0, n0, off0, ci1, n1, off1, ci2, n2, off2);
  k_place<<<(eTot + 255)/256, 256, 0, stream>>>(src0, dst0, e0, src1, dst1, e1, src2, dst2, e2,
                                                off0, off1, off2, pos0, pos1, pos2, srt0, srt1, srt2);
  k_rsq<<<((n0 + n1 + n2) + 255)/256, 256, 0, stream>>>(ci0, co0, n0, ci1, co1, n1, ci2, co2, n2,
                                                        ri0, ro0, ri1, ro1, ri2, ro2);
  // 4. level 0: Y0 = ro0 * (X @ W0); aggT -> h1t = relu(ri0*Agg(Y0) + b0) (transposed+swizzled)
  k_gemm_rs<256, 8, true><<<(n0 + 63)/64, 256, 0, stream>>>(features, wt0, ro0, Y0, n0);
  k_aggT<<<(n0 + 31)/32, 512, 0, stream>>>(Y0, srt0, off0, ri0, b0, h1t, ld1, n0);
  // 5. g1 = P1^T @ h1 (k-split + reduce)
  {
    dim3 grid(Mp1/128, S1);
    k_tn<<<grid, 256, 0, stream>>>(P1, n1, n1, n0, h1t, ld1, part1, Mp1, KPt1, cT1);
  }
  k_reduce<<<(Mp1*32 + 255)/256, 256, 0, stream>>>(part1, Mp1, S1, n1, g1, nullptr);
  // 6. level 1
  k_gemm_rs<128, 8, false><<<(n1 + 63)/64, 256, 0, stream>>>(g1, wt1, ro1, Y1, n1);
  k_aggT<<<(n1 + 31)/32, 512, 0, stream>>>(Y1, srt1, off1, ri1, b1, h2t, ld2, n1);
  // 7. emb = P2^T @ h2 (f32 out + bf16 copy)
  {
    dim3 grid(Mp2/128, S2);
    k_tn<<<grid, 256, 0, stream>>>(P2, n2, n2, n1, h2t, ld2, part2, Mp2, KPt2, cT2);
  }
  k_reduce<<<(Mp2*32 + 255)/256, 256, 0, stream>>>(part2, Mp2, S2, n2, embb, emb);
  // 8. level 2: Z2 = ro2 * (emb @ W2); out = ri2*Agg(Z2) + b2 (40 cols, f32)
  k_gemm_rs<128, 3, false><<<(n2 + 63)/64, 256, 0, stream>>>(embb, wt2, ro2, Z2, n2);
  k_agg2<<<(n2 + 3)/4, 256, 0, stream>>>(Z2, srt2, off2, ri2, b2, out, n2);
}